// Round 1
// baseline (560.560 us; speedup 1.0000x reference)
//
#include <hip/hip_runtime.h>
#include <math.h>

// GumbelSampler: iterative gumbel-softmax k-hot (k=64) over 256 rows of 16384,
// then straight-through hard top-64.
//
// Layout facts (from reference):
//   scores: (64,128,128,2) f32; flat row r: t=r>>7, be=r&127, b=be>>1, e=be&1
//     element m=i*128+j -> scores[(b*16384+m)*2 + e]
//   gumbel: (256,16384) f32, row r contiguous
//   out:    (2,64,128,128,2) f32; out[(t*64+b)*32768 + m*2 + e]
//
// One block per row; f/khot live entirely in registers.

#define BLOCK   1024
#define NWAVES  (BLOCK / 64)
#define M_ELEMS 16384
#define EPT     (M_ELEMS / BLOCK)   // 16 elements per thread
#define KSEL    64
#define TAU_F   0.1f
#define EPS_TINY 1.17549435e-38f    // np.finfo(np.float32).tiny

__global__ __launch_bounds__(BLOCK) void gumbel_topk_kernel(
    const float* __restrict__ scores,
    const float* __restrict__ gumbel,
    float* __restrict__ out)
{
    const int r    = blockIdx.x;
    const int tid  = threadIdx.x;
    const int lane = tid & 63;
    const int wid  = tid >> 6;

    const int t  = r >> 7;
    const int be = r & 127;
    const int b  = be >> 1;
    const int e  = be & 1;

    __shared__ float redA[NWAVES];
    __shared__ float redB[NWAVES];
    __shared__ int   redI[NWAVES];

    float f[EPT], kh[EPT];

    const float* gum = gumbel + (size_t)r * M_ELEMS;
    const float* sc  = scores + (size_t)b * M_ELEMS * 2 + e;

    #pragma unroll
    for (int k = 0; k < EPT; ++k) {
        const int m = tid + k * BLOCK;
        f[k]  = sc[(size_t)m * 2] + gum[m];
        kh[k] = 0.0f;
    }

    // 64 iterations of: onehot = softmax(f/tau); khot += onehot;
    //                   f += log(max(1-onehot, EPS))
    // (reference applies the f-update at the START of the next step with the
    //  previous onehot; first update is log(1)=0, last update is dead -> same)
    for (int it = 0; it < KSEL; ++it) {
        float ex[EPT];
        float lmax = -INFINITY;
        #pragma unroll
        for (int k = 0; k < EPT; ++k) {
            ex[k] = f[k] / TAU_F;          // exact div: 0.1f is not 1/10
            lmax = fmaxf(lmax, ex[k]);
        }
        #pragma unroll
        for (int off = 32; off > 0; off >>= 1)
            lmax = fmaxf(lmax, __shfl_xor(lmax, off));
        if (lane == 0) redA[wid] = lmax;
        __syncthreads();
        float gmax = redA[0];
        #pragma unroll
        for (int i = 1; i < NWAVES; ++i) gmax = fmaxf(gmax, redA[i]);

        float lsum = 0.0f;
        #pragma unroll
        for (int k = 0; k < EPT; ++k) {
            ex[k] = expf(ex[k] - gmax);
            lsum += ex[k];
        }
        #pragma unroll
        for (int off = 32; off > 0; off >>= 1)
            lsum += __shfl_xor(lsum, off);
        if (lane == 0) redB[wid] = lsum;
        __syncthreads();
        float gsum = 0.0f;
        #pragma unroll
        for (int i = 0; i < NWAVES; ++i) gsum += redB[i];

        #pragma unroll
        for (int k = 0; k < EPT; ++k) {
            const float oh = ex[k] / gsum;  // exact div to match jnp
            kh[k] += oh;
            f[k]  += logf(fmaxf(1.0f - oh, EPS_TINY));
        }
    }

    // Iterative top-64 of khot (tie-break: lower index, matching lax.top_k).
    // Work on a register copy so kh stays intact for the epilogue.
    float w[EPT];
    #pragma unroll
    for (int k = 0; k < EPT; ++k) w[k] = kh[k];
    unsigned int selmask = 0;

    for (int s = 0; s < KSEL; ++s) {
        float bv = w[0];
        int   bk = 0;
        #pragma unroll
        for (int k = 1; k < EPT; ++k)
            if (w[k] > bv) { bv = w[k]; bk = k; }   // > keeps smallest k on tie
        int bm = tid + bk * BLOCK;                   // global element index
        #pragma unroll
        for (int off = 32; off > 0; off >>= 1) {
            const float ov = __shfl_xor(bv, off);
            const int   om = __shfl_xor(bm, off);
            if (ov > bv || (ov == bv && om < bm)) { bv = ov; bm = om; }
        }
        if (lane == 0) { redA[wid] = bv; redI[wid] = bm; }
        __syncthreads();
        float gv = redA[0];
        int   gm = redI[0];
        #pragma unroll
        for (int i = 1; i < NWAVES; ++i) {
            const float ov = redA[i];
            const int   om = redI[i];
            if (ov > gv || (ov == gv && om < gm)) { gv = ov; gm = om; }
        }
        __syncthreads();

        // Winner thread clears its element (static-indexed predicated write:
        // runtime-indexed register arrays would spill to scratch).
        const bool mine = ((gm & (BLOCK - 1)) == tid);
        const int  ks   = gm >> 10;                 // log2(BLOCK)
        if (mine) selmask |= (1u << ks);
        #pragma unroll
        for (int kk = 0; kk < EPT; ++kk)
            if (mine && kk == ks) w[kk] = -INFINITY;
    }

    // res = (khot_hard - khot) + khot, written to out[t,b,i,j,e]
    float* orow = out + (size_t)(t * 64 + b) * (M_ELEMS * 2) + e;
    #pragma unroll
    for (int k = 0; k < EPT; ++k) {
        const int   m    = tid + k * BLOCK;
        const float hard = ((selmask >> k) & 1u) ? 1.0f : 0.0f;
        orow[(size_t)m * 2] = (hard - kh[k]) + kh[k];
    }
}

extern "C" void kernel_launch(void* const* d_in, const int* in_sizes, int n_in,
                              void* d_out, int out_size, void* d_ws, size_t ws_size,
                              hipStream_t stream) {
    const float* scores = (const float*)d_in[0];
    const float* gumbel = (const float*)d_in[1];
    float* out = (float*)d_out;
    // rows = train_ensemble * bsz * ensemble = 2*64*2 = 256
    const int rows = in_sizes[1] / M_ELEMS;
    gumbel_topk_kernel<<<rows, BLOCK, 0, stream>>>(scores, gumbel, out);
}

// Round 2
// 319.168 us; speedup vs baseline: 1.7563x; 1.7563x over previous
//
#include <hip/hip_runtime.h>
#include <math.h>

// GumbelSampler: iterative gumbel-softmax k-hot (k=64) over 256 rows of 16384,
// then straight-through hard top-64. One block per row (grid 256 = 1 block/CU).
//
// Output is exactly binary ((hard-kh)+kh == hard in f32), so only the top-64
// SELECTION must match the reference -> fast-math transcendentals are safe.
//
// Key structure: softmax is shift-invariant, and f only decreases
// (f += log(max(1-oh,EPS)) <= 0), so exp() against the PREVIOUS iteration's
// row-max never overflows. The fresh max rides in the same butterfly as the
// sum -> ONE barrier per iteration. A block-uniform guard redoes the sum with
// the fresh max in the rare case the per-iteration max-drop (top-gap > ~3.5)
// underflows everything.

#define BLOCK   1024
#define NWAVES  (BLOCK / 64)        // 16
#define M_ELEMS 16384
#define EPT     (M_ELEMS / BLOCK)   // 16 elements per thread
#define KSEL    64
#define EPS_TINY 1.17549435e-38f    // np.finfo(np.float32).tiny
#define C_EXP    14.426950408889634f // 10 * log2(e)  (exp(x/tau) = exp2(x*C))
#define LN2_F    0.6931471805599453f

__global__ __launch_bounds__(BLOCK, 4) void gumbel_topk_kernel(
    const float* __restrict__ scores,
    const float* __restrict__ gumbel,
    float* __restrict__ out)
{
    const int tid  = threadIdx.x;
    const int lane = tid & 63;
    const int wid  = tid >> 6;
    const int r  = blockIdx.x;
    const int t  = r >> 7;
    const int be = r & 127;
    const int b  = be >> 1;
    const int e  = be & 1;

    __shared__ float redS[2][NWAVES];   // sum partials (double-buffered)
    __shared__ float redM[2][NWAVES];   // max partials
    __shared__ int   redI[2][NWAVES];   // argmax partials (selection phase)

    float f[EPT], kh[EPT];
    const float* gum = gumbel + (size_t)r * M_ELEMS;
    const float* sc  = scores + (size_t)b * (M_ELEMS * 2) + e;

    #pragma unroll
    for (int k = 0; k < EPT; ++k) {
        const int m = tid + k * BLOCK;
        f[k]  = sc[(size_t)m * 2] + gum[m];
        kh[k] = 0.0f;
    }

    // ---- prologue: exact initial row max -> mrow (block-uniform) ----
    float lmax = -INFINITY;
    #pragma unroll
    for (int k = 0; k < EPT; ++k) lmax = fmaxf(lmax, f[k]);
    #pragma unroll
    for (int off = 32; off; off >>= 1) lmax = fmaxf(lmax, __shfl_xor(lmax, off));
    if (lane == 0) redS[1][wid] = lmax;   // redS[1]: next written at it=1, after it=0's barrier
    __syncthreads();
    float mrow = redS[1][lane & (NWAVES - 1)];
    #pragma unroll
    for (int off = 1; off < NWAVES; off <<= 1)
        mrow = fmaxf(mrow, __shfl_xor(mrow, off));

    // ---- main loop: 64 x { softmax(f/tau); kh += oh; f += log(max(1-oh,EPS)) }
    for (int it = 0; it < KSEL; ++it) {
        const int buf = it & 1;
        const float marg = mrow * C_EXP;
        float ex[EPT];
        float lsum = 0.0f;
        lmax = -INFINITY;
        #pragma unroll
        for (int k = 0; k < EPT; ++k) {
            ex[k] = __expf(fmaf(f[k], 10.0f, -mrow * 10.0f)); // exp((f-m)*10)
            lsum += ex[k];
            lmax  = fmaxf(lmax, f[k]);        // fresh max rides along for free
        }
        (void)marg;
        #pragma unroll
        for (int off = 32; off; off >>= 1) {
            lsum += __shfl_xor(lsum, off);
            lmax  = fmaxf(lmax, __shfl_xor(lmax, off));
        }
        if (lane == 0) { redS[buf][wid] = lsum; redM[buf][wid] = lmax; }
        __syncthreads();
        float gsum = redS[buf][lane & (NWAVES - 1)];
        float gmax = redM[buf][lane & (NWAVES - 1)];
        #pragma unroll
        for (int off = 1; off < NWAVES; off <<= 1) {
            gsum += __shfl_xor(gsum, off);
            gmax  = fmaxf(gmax, __shfl_xor(gmax, off));
        }

        // rare, block-uniform guard: stale max dropped so far everything
        // underflowed -> redo this iteration's exps with the fresh max.
        if (gsum < 1e-15f) {
            const float marg2 = gmax * 10.0f;
            lsum = 0.0f;
            #pragma unroll
            for (int k = 0; k < EPT; ++k) {
                ex[k] = __expf(fmaf(f[k], 10.0f, -marg2));
                lsum += ex[k];
            }
            #pragma unroll
            for (int off = 32; off; off >>= 1) lsum += __shfl_xor(lsum, off);
            __syncthreads();                       // prior reads of redS[buf] done
            if (lane == 0) redS[buf][wid] = lsum;
            __syncthreads();
            gsum = redS[buf][lane & (NWAVES - 1)];
            #pragma unroll
            for (int off = 1; off < NWAVES; off <<= 1) gsum += __shfl_xor(gsum, off);
        }

        const float rsum = 1.0f / gsum;   // one division per iteration
        #pragma unroll
        for (int k = 0; k < EPT; ++k) {
            const float oh = ex[k] * rsum;
            kh[k] += oh;
            const float tt = fmaxf(1.0f - oh, EPS_TINY);
            f[k] = fmaf(__logf(tt), 1.0f, f[k]);   // f += ln(tt)
        }
        mrow = gmax;
    }

    // ---- iterative top-64 of khot (tie-break: lower index == lax.top_k) ----
    float w[EPT];
    #pragma unroll
    for (int k = 0; k < EPT; ++k) w[k] = kh[k];
    unsigned int selmask = 0;

    for (int s = 0; s < KSEL; ++s) {
        const int buf = s & 1;
        float bv = w[0];
        int   bk = 0;
        #pragma unroll
        for (int k = 1; k < EPT; ++k)
            if (w[k] > bv) { bv = w[k]; bk = k; }    // strict > keeps lowest k
        int bm = tid + bk * BLOCK;
        #pragma unroll
        for (int off = 32; off; off >>= 1) {
            const float ov = __shfl_xor(bv, off);
            const int   om = __shfl_xor(bm, off);
            if (ov > bv || (ov == bv && om < bm)) { bv = ov; bm = om; }
        }
        if (lane == 0) { redM[buf][wid] = bv; redI[buf][wid] = bm; }
        __syncthreads();
        float gv = redM[buf][lane & (NWAVES - 1)];
        int   gm = redI[buf][lane & (NWAVES - 1)];
        #pragma unroll
        for (int off = 1; off < NWAVES; off <<= 1) {
            const float ov = __shfl_xor(gv, off);
            const int   om = __shfl_xor(gm, off);
            if (ov > gv || (ov == gv && om < gm)) { gv = ov; gm = om; }
        }
        // winner thread clears its element (static-indexed predicated writes)
        const bool mine = ((gm & (BLOCK - 1)) == tid);
        const int  ks   = gm >> 10;                  // log2(BLOCK)
        if (mine) selmask |= (1u << ks);
        #pragma unroll
        for (int kk = 0; kk < EPT; ++kk)
            if (mine && kk == ks) w[kk] = -INFINITY;
    }

    // ---- res = (hard - kh) + kh == hard exactly; out[t,b,i,j,e] ----
    float* orow = out + (size_t)(t * 64 + b) * (M_ELEMS * 2) + e;
    #pragma unroll
    for (int k = 0; k < EPT; ++k) {
        const int   m    = tid + k * BLOCK;
        const float hard = ((selmask >> k) & 1u) ? 1.0f : 0.0f;
        orow[(size_t)m * 2] = (hard - kh[k]) + kh[k];
    }
}

extern "C" void kernel_launch(void* const* d_in, const int* in_sizes, int n_in,
                              void* d_out, int out_size, void* d_ws, size_t ws_size,
                              hipStream_t stream) {
    const float* scores = (const float*)d_in[0];
    const float* gumbel = (const float*)d_in[1];
    float* out = (float*)d_out;
    const int rows = in_sizes[1] / M_ELEMS;   // 256
    gumbel_topk_kernel<<<rows, BLOCK, 0, stream>>>(scores, gumbel, out);
}

// Round 3
// 208.565 us; speedup vs baseline: 2.6877x; 1.5303x over previous
//
#include <hip/hip_runtime.h>
#include <math.h>

// GumbelSampler: iterative gumbel-softmax k-hot (k=64) over 256 rows of 16384,
// then straight-through hard top-64. One block per row (grid 256 = 1 block/CU).
//
// Output is exactly binary, so only the top-64 SELECTION must match the
// reference -> 1-ulp transcendentals are safe (round 1/2 passed absmax=0.0
// with larger perturbations than these).
//
// exp(x/tau) computed as exp2(x*C), C = 10*log2(e); f += ln(t) computed as
// f += log2(t)*ln2 -- raw v_exp_f32 / v_log_f32 (quarter-rate) instead of
// ocml sequences (~25 full-rate ops each), which round-2 counters showed
// dominating VALU issue.
//
// Softmax is shift-invariant and f only decreases, so exp against the
// PREVIOUS iteration's row-max never overflows; fresh max rides in the same
// butterfly as the sum -> ONE barrier per iteration. Block-uniform underflow
// guard (gsum < 1e-15) redoes the iteration with the fresh max.

#define BLOCK   1024
#define NWAVES  (BLOCK / 64)        // 16
#define M_ELEMS 16384
#define EPT     (M_ELEMS / BLOCK)   // 16 elements per thread
#define KSEL    64
#define EPS_TINY 1.17549435e-38f    // np.finfo(np.float32).tiny
#define C_EXP    14.426950408889634f // 10 * log2(e)
#define LN2F     0.6931471805599453f

__global__ __launch_bounds__(BLOCK, 4) void gumbel_topk_kernel(
    const float* __restrict__ scores,
    const float* __restrict__ gumbel,
    float* __restrict__ out)
{
    const int tid  = threadIdx.x;
    const int lane = tid & 63;
    const int wid  = tid >> 6;
    const int r  = blockIdx.x;
    const int t  = r >> 7;
    const int be = r & 127;
    const int b  = be >> 1;
    const int e  = be & 1;

    __shared__ float redS[2][NWAVES];   // sum partials (double-buffered)
    __shared__ float redM[2][NWAVES];   // max partials
    __shared__ int   redI[2][NWAVES];   // argmax partials (selection phase)

    float f[EPT], kh[EPT];
    const float* gum = gumbel + (size_t)r * M_ELEMS;
    const float* sc  = scores + (size_t)b * (M_ELEMS * 2) + e;

    #pragma unroll
    for (int k = 0; k < EPT; ++k) {
        const int m = tid + k * BLOCK;
        f[k]  = sc[(size_t)m * 2] + gum[m];
        kh[k] = 0.0f;
    }

    // ---- prologue: exact initial row max -> mrow (block-uniform) ----
    {
        float lmax = -INFINITY;
        #pragma unroll
        for (int k = 0; k < EPT; ++k) lmax = fmaxf(lmax, f[k]);
        #pragma unroll
        for (int off = 32; off; off >>= 1) lmax = fmaxf(lmax, __shfl_xor(lmax, off));
        if (lane == 0) redM[1][wid] = lmax;  // buf1: next written at it=1, after it=0's barrier
        __syncthreads();
    }
    float mrow = redM[1][lane & (NWAVES - 1)];
    #pragma unroll
    for (int off = 1; off < NWAVES; off <<= 1)
        mrow = fmaxf(mrow, __shfl_xor(mrow, off));

    // ---- main loop: 64 x { softmax(f/tau); kh += oh; f += log(max(1-oh,EPS)) }
    for (int it = 0; it < KSEL; ++it) {
        const int buf = it & 1;
        const float nmC = -mrow * C_EXP;
        float ex[EPT];
        float lsum = 0.0f;
        float lmax = -INFINITY;
        #pragma unroll
        for (int k = 0; k < EPT; ++k) {
            ex[k] = __builtin_amdgcn_exp2f(fmaf(f[k], C_EXP, nmC)); // exp((f-m)*10)
            lsum += ex[k];
            lmax  = fmaxf(lmax, f[k]);      // fresh max rides along
        }
        #pragma unroll
        for (int off = 32; off; off >>= 1) {
            lsum += __shfl_xor(lsum, off);
            lmax  = fmaxf(lmax, __shfl_xor(lmax, off));
        }
        if (lane == 0) { redS[buf][wid] = lsum; redM[buf][wid] = lmax; }
        __syncthreads();
        float gsum = redS[buf][lane & (NWAVES - 1)];
        float gmax = redM[buf][lane & (NWAVES - 1)];
        #pragma unroll
        for (int off = 1; off < NWAVES; off <<= 1) {
            gsum += __shfl_xor(gsum, off);
            gmax  = fmaxf(gmax, __shfl_xor(gmax, off));
        }

        // rare, block-uniform guard: stale max dropped so far everything
        // underflowed -> redo this iteration's exps with the fresh max.
        if (gsum < 1e-15f) {
            const float nmC2 = -gmax * C_EXP;
            lsum = 0.0f;
            #pragma unroll
            for (int k = 0; k < EPT; ++k) {
                ex[k] = __builtin_amdgcn_exp2f(fmaf(f[k], C_EXP, nmC2));
                lsum += ex[k];
            }
            #pragma unroll
            for (int off = 32; off; off >>= 1) lsum += __shfl_xor(lsum, off);
            __syncthreads();                 // prior reads of redS[buf] done
            if (lane == 0) redS[buf][wid] = lsum;
            __syncthreads();
            gsum = redS[buf][lane & (NWAVES - 1)];
            #pragma unroll
            for (int off = 1; off < NWAVES; off <<= 1) gsum += __shfl_xor(gsum, off);
        }

        const float rsum = __builtin_amdgcn_rcpf(gsum);  // 1-ulp rcp, once/iter
        #pragma unroll
        for (int k = 0; k < EPT; ++k) {
            const float oh = ex[k] * rsum;
            kh[k] += oh;
            const float tt = fmaxf(1.0f - oh, EPS_TINY);
            f[k] = fmaf(__builtin_amdgcn_logf(tt), LN2F, f[k]);  // f += ln(tt)
        }
        mrow = gmax;
    }

    // ---- iterative top-64 of khot (tie-break: lower index == lax.top_k) ----
    // Cached per-thread local argmax: only the single thread whose winner was
    // cleared rescans its 16 registers (other waves skip via execz).
    float w[EPT];
    #pragma unroll
    for (int k = 0; k < EPT; ++k) w[k] = kh[k];
    unsigned int selmask = 0;

    float bv = w[0];
    int   bk = 0;
    #pragma unroll
    for (int k = 1; k < EPT; ++k)
        if (w[k] > bv) { bv = w[k]; bk = k; }    // strict > keeps lowest index

    for (int s = 0; s < KSEL; ++s) {
        const int buf = s & 1;
        float cv = bv;
        int   cm = tid + (bk << 10);             // global element index
        #pragma unroll
        for (int off = 32; off; off >>= 1) {
            const float ov = __shfl_xor(cv, off);
            const int   om = __shfl_xor(cm, off);
            if (ov > cv || (ov == cv && om < cm)) { cv = ov; cm = om; }
        }
        if (lane == 0) { redM[buf][wid] = cv; redI[buf][wid] = cm; }
        __syncthreads();
        float gv = redM[buf][lane & (NWAVES - 1)];
        int   gm = redI[buf][lane & (NWAVES - 1)];
        #pragma unroll
        for (int off = 1; off < NWAVES; off <<= 1) {
            const float ov = __shfl_xor(gv, off);
            const int   om = __shfl_xor(gm, off);
            if (ov > gv || (ov == gv && om < gm)) { gv = ov; gm = om; }
        }
        // winner thread: record, clear, rescan cache (static indices only)
        if (((gm & (BLOCK - 1)) == tid)) {
            const int ks = gm >> 10;
            selmask |= (1u << ks);
            #pragma unroll
            for (int kk = 0; kk < EPT; ++kk)
                if (kk == ks) w[kk] = -INFINITY;
            bv = w[0]; bk = 0;
            #pragma unroll
            for (int k = 1; k < EPT; ++k)
                if (w[k] > bv) { bv = w[k]; bk = k; }
        }
    }

    // ---- res = (hard - kh) + kh; out[t,b,i,j,e] ----
    float* orow = out + (size_t)(t * 64 + b) * (M_ELEMS * 2) + e;
    #pragma unroll
    for (int k = 0; k < EPT; ++k) {
        const int   m    = tid + k * BLOCK;
        const float hard = ((selmask >> k) & 1u) ? 1.0f : 0.0f;
        orow[(size_t)m * 2] = (hard - kh[k]) + kh[k];
    }
}

extern "C" void kernel_launch(void* const* d_in, const int* in_sizes, int n_in,
                              void* d_out, int out_size, void* d_ws, size_t ws_size,
                              hipStream_t stream) {
    const float* scores = (const float*)d_in[0];
    const float* gumbel = (const float*)d_in[1];
    float* out = (float*)d_out;
    const int rows = in_sizes[1] / M_ELEMS;   // 256
    gumbel_topk_kernel<<<rows, BLOCK, 0, stream>>>(scores, gumbel, out);
}

// Round 4
// 166.115 us; speedup vs baseline: 3.3745x; 1.2555x over previous
//
#include <hip/hip_runtime.h>
#include <math.h>

// GumbelSampler: iterative gumbel-softmax k-hot (k=64) over 256 rows of 16384,
// then straight-through hard top-64. One block per row (grid 256 = 1 block/CU).
//
// Round-4 restructure: the whole scan runs in EX-SPACE.
//   ref: f += ln(max(1-oh,EPS));  softmax(f/tau) each iter
//   here: ex tracks exp((f-base)/tau); update is ex *= t^10 (t=1-oh, tau=0.1)
//         computed as t2=t*t, t4=t2*t2, t8=t4*t4, ex*t8*t2 -> NO exp/log in loop.
// Cold elements (oh < 2^-25) have t==1.0f exactly -> ex untouched, bit-stable.
// f32 exponent-range management: base is chosen so top ex ~= 2^60; whenever
// gsum < 2^50 (checked from its exponent bits, block-uniform) all ex are
// rescaled by an exact power of 2 targeting gsum ~= 2^60 (exact, no rounding).
// Down-room to flush ~176 bits ~= 12 natural units of single-iteration gap.
//
// Only the top-64 SELECTION must match the reference (output is exactly
// binary); rounds 1-3 passed absmax 0.0 with same-scale perturbations.

#define BLOCK   1024
#define NWAVES  (BLOCK / 64)        // 16
#define M_ELEMS 16384
#define EPT     (M_ELEMS / BLOCK)   // 16 elements per thread
#define KSEL    64
#define C10     14.42695019f        // log2(e)/0.1f  (exp(x/tau) = exp2(x*C10))

__global__ __launch_bounds__(BLOCK, 4) void gumbel_topk_kernel(
    const float* __restrict__ scores,
    const float* __restrict__ gumbel,
    float* __restrict__ out)
{
    const int tid  = threadIdx.x;
    const int lane = tid & 63;
    const int wid  = tid >> 6;
    const int r  = blockIdx.x;
    const int t_ = r >> 7;
    const int be = r & 127;
    const int b  = be >> 1;
    const int e  = be & 1;

    __shared__ float redS[2][NWAVES];
    __shared__ float redM[2][NWAVES];
    __shared__ int   redI[2][NWAVES];

    float ex[EPT], kh[EPT];
    const float* gum = gumbel + (size_t)r * M_ELEMS;
    const float* sc  = scores + (size_t)b * (M_ELEMS * 2) + e;

    float f0[EPT];
    #pragma unroll
    for (int k = 0; k < EPT; ++k) {
        const int m = tid + k * BLOCK;
        f0[k] = sc[(size_t)m * 2] + gum[m];
        kh[k] = 0.0f;
    }

    // ---- prologue: row max m0 -> base; ex = exp2((f0-m0)*C10 + 60) ----
    {
        float lmax = -INFINITY;
        #pragma unroll
        for (int k = 0; k < EPT; ++k) lmax = fmaxf(lmax, f0[k]);
        #pragma unroll
        for (int off = 32; off; off >>= 1) lmax = fmaxf(lmax, __shfl_xor(lmax, off));
        if (lane == 0) redM[0][wid] = lmax;
        __syncthreads();
    }
    {
        float m0 = redM[0][lane & (NWAVES - 1)];
        #pragma unroll
        for (int off = 1; off < NWAVES; off <<= 1)
            m0 = fmaxf(m0, __shfl_xor(m0, off));
        const float nb = fmaf(-m0, C10, 60.0f);   // -m0*C10 + 60
        #pragma unroll
        for (int k = 0; k < EPT; ++k)
            ex[k] = __builtin_amdgcn_exp2f(fmaf(f0[k], C10, nb));
    }

    // ---- main loop: 64 x { gsum; oh=ex/gsum; kh+=oh; ex *= (1-oh)^10 } ----
    for (int it = 0; it < KSEL; ++it) {
        const int buf = it & 1;
        float lsum = 0.0f;
        #pragma unroll
        for (int k = 0; k < EPT; ++k) lsum += ex[k];
        #pragma unroll
        for (int off = 32; off; off >>= 1) lsum += __shfl_xor(lsum, off);
        if (lane == 0) redS[buf][wid] = lsum;
        __syncthreads();
        float gsum = redS[buf][lane & (NWAVES - 1)];
        #pragma unroll
        for (int off = 1; off < NWAVES; off <<= 1) gsum += __shfl_xor(gsum, off);

        // exponent-range rebase (block-uniform, rare: ~2-3x per row)
        const int eb = (int)((__float_as_uint(gsum) >> 23) & 0xFF);
        if (eb < 127 + 50) {              // gsum < 2^50 (incl. denorm/zero)
            int sh = 314 - eb;            // biased exp of s = 2^(60-(eb-127))
            if (sh > 254) sh = 254;       // cap at 2^127
            const float s = __uint_as_float((unsigned)sh << 23);
            float ls2 = 0.0f;
            #pragma unroll
            for (int k = 0; k < EPT; ++k) { ex[k] *= s; ls2 += ex[k]; }
            #pragma unroll
            for (int off = 32; off; off >>= 1) ls2 += __shfl_xor(ls2, off);
            __syncthreads();              // prior redS[buf] reads done
            if (lane == 0) redS[buf][wid] = ls2;
            __syncthreads();
            gsum = redS[buf][lane & (NWAVES - 1)];
            #pragma unroll
            for (int off = 1; off < NWAVES; off <<= 1) gsum += __shfl_xor(gsum, off);
            if (!(gsum > 0.0f)) gsum = INFINITY;  // dead row -> no-op iters
        }

        const float rsum = __builtin_amdgcn_rcpf(gsum);
        #pragma unroll
        for (int k = 0; k < EPT; ++k) {
            kh[k] = fmaf(ex[k], rsum, kh[k]);          // kh += oh
            const float t  = fmaf(-ex[k], rsum, 1.0f); // t = 1 - oh
            const float t2 = t * t;
            const float t4 = t2 * t2;
            const float t8 = t4 * t4;
            ex[k] = ex[k] * t8 * t2;                   // ex *= t^10
        }
    }

    // ---- iterative top-64 of khot (tie-break: lower index == lax.top_k) ----
    float w[EPT];
    #pragma unroll
    for (int k = 0; k < EPT; ++k) w[k] = kh[k];
    unsigned int selmask = 0;

    float bv = w[0];
    int   bk = 0;
    #pragma unroll
    for (int k = 1; k < EPT; ++k)
        if (w[k] > bv) { bv = w[k]; bk = k; }    // strict > keeps lowest index

    for (int s = 0; s < KSEL; ++s) {
        const int buf = s & 1;
        float cv = bv;
        int   cm = tid + (bk << 10);             // global element index
        #pragma unroll
        for (int off = 32; off; off >>= 1) {
            const float ov = __shfl_xor(cv, off);
            const int   om = __shfl_xor(cm, off);
            if (ov > cv || (ov == cv && om < cm)) { cv = ov; cm = om; }
        }
        if (lane == 0) { redM[buf][wid] = cv; redI[buf][wid] = cm; }
        __syncthreads();
        float gv = redM[buf][lane & (NWAVES - 1)];
        int   gm = redI[buf][lane & (NWAVES - 1)];
        #pragma unroll
        for (int off = 1; off < NWAVES; off <<= 1) {
            const float ov = __shfl_xor(gv, off);
            const int   om = __shfl_xor(gm, off);
            if (ov > gv || (ov == gv && om < gm)) { gv = ov; gm = om; }
        }
        // winner thread: record, clear, rescan cache (static indices only)
        if (((gm & (BLOCK - 1)) == tid)) {
            const int ks = gm >> 10;
            selmask |= (1u << ks);
            #pragma unroll
            for (int kk = 0; kk < EPT; ++kk)
                if (kk == ks) w[kk] = -INFINITY;
            bv = w[0]; bk = 0;
            #pragma unroll
            for (int k = 1; k < EPT; ++k)
                if (w[k] > bv) { bv = w[k]; bk = k; }
        }
    }

    // ---- res = (hard - kh) + kh; out[t,b,i,j,e] ----
    float* orow = out + (size_t)(t_ * 64 + b) * (M_ELEMS * 2) + e;
    #pragma unroll
    for (int k = 0; k < EPT; ++k) {
        const int   m    = tid + k * BLOCK;
        const float hard = ((selmask >> k) & 1u) ? 1.0f : 0.0f;
        orow[(size_t)m * 2] = (hard - kh[k]) + kh[k];
    }
}

extern "C" void kernel_launch(void* const* d_in, const int* in_sizes, int n_in,
                              void* d_out, int out_size, void* d_ws, size_t ws_size,
                              hipStream_t stream) {
    const float* scores = (const float*)d_in[0];
    const float* gumbel = (const float*)d_in[1];
    float* out = (float*)d_out;
    const int rows = in_sizes[1] / M_ELEMS;   // 256
    gumbel_topk_kernel<<<rows, BLOCK, 0, stream>>>(scores, gumbel, out);
}

// Round 5
// 135.116 us; speedup vs baseline: 4.1487x; 1.2294x over previous
//
#include <hip/hip_runtime.h>
#include <math.h>

// GumbelSampler: iterative gumbel-softmax k-hot (k=64) over 256 rows of 16384,
// then straight-through hard top-64. One block per row (grid 256 = 1 block/CU).
//
// Round-5 restructure: CANDIDATE COMPACTION. tau=0.1 makes softmax so peaked
// that only elements within ~0.17 (natural units) of the running max ever get
// oh >= 2^-25; since ex only shrinks, the ever-warm set over 64 iterations is
// within the initial top ~150. We select the top ~1024 by initial value
// (radix histogram, 6x margin), then run the ENTIRE 64-iteration dynamics on
// one wave in registers -- no block barriers in the hot loops (was ~128).
// Excluded tail contributes <=1e-10 rel to gsum, <=2e-6 to kh: far below
// selection margins. Output is exactly binary ((1-kh)+kh is Sterbenz-exact;
// rounds 1-4 passed absmax 0.0), so we write the 0/1 mask directly.
//
// Determinism: histogram uses commutative integer atomics; compaction is
// prefix-sum-ordered; dynamics order fixed -> bitwise-stable across replays.

#define BLOCK   1024
#define NWAVES  16
#define M_ELEMS 16384
#define EPT     16                  // elements per thread in block phases
#define KSEL    64
#define NCAND   1024                // candidate capacity
#define CPL     16                  // candidates per lane in wave0
#define NBINS   4096                // radix bins: f32 bits >> 19 (sign always 0)
#define C10     14.42695019f        // log2(e)/tau

__global__ __launch_bounds__(BLOCK, 4) void gumbel_topk_kernel(
    const float* __restrict__ scores,
    const float* __restrict__ gumbel,
    float* __restrict__ out)
{
    const int tid  = threadIdx.x;
    const int lane = tid & 63;
    const int wid  = tid >> 6;
    const int r  = blockIdx.x;
    const int t_ = r >> 7;
    const int be = r & 127;
    const int b  = be >> 1;
    const int e  = be & 1;

    __shared__ unsigned int hist[NBINS];        // 16 KB
    __shared__ float        exbuf[NCAND];       // 4 KB
    __shared__ unsigned int idxbuf[NCAND];      // 4 KB
    __shared__ unsigned int bitmap[M_ELEMS/32]; // 2 KB
    __shared__ float        redF[NWAVES];
    __shared__ unsigned int wofs[NWAVES];
    __shared__ unsigned int cutbin;
    __shared__ unsigned int candcnt;

    // ---- P0: load f0, zero hist+bitmap, row max ----
    float ex[EPT];
    {
        const float* gum = gumbel + (size_t)r * M_ELEMS;
        const float* sc  = scores + (size_t)b * (M_ELEMS * 2) + e;
        #pragma unroll
        for (int k = 0; k < EPT; ++k) {
            const int m = tid + (k << 10);
            ex[k] = sc[(size_t)m * 2] + gum[m];     // f0 for now
        }
    }
    #pragma unroll
    for (int k = 0; k < NBINS / BLOCK; ++k) hist[tid + k * BLOCK] = 0u;
    if (tid < M_ELEMS / 32) bitmap[tid] = 0u;

    float lmax = -INFINITY;
    #pragma unroll
    for (int k = 0; k < EPT; ++k) lmax = fmaxf(lmax, ex[k]);
    #pragma unroll
    for (int off = 32; off; off >>= 1) lmax = fmaxf(lmax, __shfl_xor(lmax, off));
    if (lane == 0) redF[wid] = lmax;
    __syncthreads();
    float m0 = redF[lane & (NWAVES - 1)];
    #pragma unroll
    for (int off = 1; off < NWAVES; off <<= 1)
        m0 = fmaxf(m0, __shfl_xor(m0, off));

    // ex = exp2((f0 - m0)*C10 + 60): positive, monotone in f0
    const float nb = fmaf(-m0, C10, 60.0f);
    #pragma unroll
    for (int k = 0; k < EPT; ++k)
        ex[k] = __builtin_amdgcn_exp2f(fmaf(ex[k], C10, nb));

    // ---- P1a: histogram of ex bit-patterns (monotone for x >= 0) ----
    #pragma unroll
    for (int k = 0; k < EPT; ++k)
        atomicAdd(&hist[__float_as_uint(ex[k]) >> 19], 1u);
    __syncthreads();

    // ---- P1b: wave0 finds cutoff = min bin with CntGE(bin) <= NCAND ----
    if (wid == 0) {
        unsigned part = 0;
        #pragma unroll 8
        for (int j = 0; j < NBINS / 64; ++j) part += hist[lane * (NBINS / 64) + j];
        unsigned suf = part;                       // inclusive suffix sum over lanes
        #pragma unroll
        for (int off = 1; off < 64; off <<= 1) {
            const unsigned y = __shfl_down(suf, off);
            if (lane + off < 64) suf += y;
        }
        const unsigned long long mk = __ballot(suf > NCAND);  // suf_0=16384>NCAND
        const int L = 63 - __builtin_clzll(mk);    // highest lane with suf > NCAND
        const unsigned sufNext = __shfl_down(suf, 1);
        if (lane == L) {
            unsigned running = (L == 63) ? 0u : sufNext;   // CntGE(chunk top+1)
            const int base = L * (NBINS / 64);
            for (int bb = base + (NBINS / 64) - 1; bb >= base; --bb) {
                const unsigned h = hist[bb];
                running += h;
                if (running > NCAND) {             // crossing found
                    cutbin  = (unsigned)(bb + 1);
                    candcnt = running - h;         // CntGE(bb+1) <= NCAND
                    break;
                }
            }
        }
    }
    __syncthreads();
    const unsigned cutKey = cutbin << 19;
    const unsigned nc     = candcnt;

    // ---- P1c: deterministic prefix-ordered compaction into LDS ----
    unsigned mycnt = 0, hitm = 0;
    #pragma unroll
    for (int k = 0; k < EPT; ++k) {
        const bool c = __float_as_uint(ex[k]) >= cutKey;
        hitm |= (c ? 1u : 0u) << k;
        mycnt += c ? 1u : 0u;
    }
    unsigned inc = mycnt;                          // wave inclusive prefix
    #pragma unroll
    for (int off = 1; off < 64; off <<= 1) {
        const unsigned y = __shfl_up(inc, off);
        if (lane >= off) inc += y;
    }
    if (lane == 63) wofs[wid] = inc;
    __syncthreads();
    unsigned wbase = 0;
    #pragma unroll
    for (int i = 0; i < NWAVES; ++i) wbase += (i < wid) ? wofs[i] : 0u;
    unsigned slot = wbase + inc - mycnt;
    #pragma unroll
    for (int k = 0; k < EPT; ++k) {
        if ((hitm >> k) & 1u) {
            exbuf[slot]  = ex[k];
            idxbuf[slot] = (unsigned)(tid + (k << 10));
            ++slot;
        }
    }
    if ((unsigned)tid >= nc) {                     // pad slots [nc, 1024)
        exbuf[tid]  = 0.0f;
        idxbuf[tid] = 0x7fffffffu;
    }
    __syncthreads();

    // ---- P2+P3: single-wave dynamics + top-64 (no block barriers) ----
    if (wid == 0) {
        float    cex[CPL], ckh[CPL];
        unsigned cidx[CPL];
        #pragma unroll
        for (int k = 0; k < CPL; ++k) {
            cex[k]  = exbuf[lane + (k << 6)];
            cidx[k] = idxbuf[lane + (k << 6)];
            ckh[k]  = 0.0f;
        }

        for (int it = 0; it < KSEL; ++it) {
            float lsum = 0.0f;
            #pragma unroll
            for (int k = 0; k < CPL; ++k) lsum += cex[k];
            #pragma unroll
            for (int off = 32; off; off >>= 1) lsum += __shfl_xor(lsum, off);
            float gsum = lsum;

            // exponent-range rebase (wave-uniform, rare)
            const int eb = (int)((__float_as_uint(gsum) >> 23) & 0xFF);
            if (eb < 127 + 50) {
                int sh = 314 - eb;
                if (sh > 254) sh = 254;
                const float s = __uint_as_float((unsigned)sh << 23);
                lsum = 0.0f;
                #pragma unroll
                for (int k = 0; k < CPL; ++k) { cex[k] *= s; lsum += cex[k]; }
                #pragma unroll
                for (int off = 32; off; off >>= 1) lsum += __shfl_xor(lsum, off);
                gsum = lsum;
                if (!(gsum > 0.0f)) gsum = INFINITY;
            }

            const float rsum = __builtin_amdgcn_rcpf(gsum);
            #pragma unroll
            for (int k = 0; k < CPL; ++k) {
                ckh[k] = fmaf(cex[k], rsum, ckh[k]);          // kh += oh
                const float t  = fmaf(-cex[k], rsum, 1.0f);   // 1 - oh
                const float t2 = t * t;
                const float t4 = t2 * t2;
                const float t8 = t4 * t4;
                cex[k] = cex[k] * t8 * t2;                    // ex *= t^10
            }
        }

        // top-64 with cached local argmax; ties -> smaller global index
        float w[CPL];
        #pragma unroll
        for (int k = 0; k < CPL; ++k) w[k] = ckh[k];
        float    bv   = w[0];
        unsigned bidx = cidx[0];
        int      bk   = 0;
        #pragma unroll
        for (int k = 1; k < CPL; ++k)
            if (w[k] > bv || (w[k] == bv && cidx[k] < bidx)) {
                bv = w[k]; bidx = cidx[k]; bk = k;
            }

        unsigned selwin = 0xffffffffu;   // lane s holds round-s winner
        for (int s = 0; s < KSEL; ++s) {
            float    cv = bv;
            unsigned ci = bidx;
            #pragma unroll
            for (int off = 32; off; off >>= 1) {
                const float    ov = __shfl_xor(cv, off);
                const unsigned oi = __shfl_xor(ci, off);
                if (ov > cv || (ov == cv && oi < ci)) { cv = ov; ci = oi; }
            }
            if (lane == s) selwin = ci;
            if (ci == bidx) {            // unique global idx -> I own winner
                #pragma unroll
                for (int kk = 0; kk < CPL; ++kk)
                    if (kk == bk) w[kk] = -INFINITY;
                bv = w[0]; bidx = cidx[0]; bk = 0;
                #pragma unroll
                for (int k = 1; k < CPL; ++k)
                    if (w[k] > bv || (w[k] == bv && cidx[k] < bidx)) {
                        bv = w[k]; bidx = cidx[k]; bk = k;
                    }
            }
        }
        if (selwin < M_ELEMS)
            atomicOr(&bitmap[selwin >> 5], 1u << (selwin & 31));
    }
    __syncthreads();

    // ---- P4: write binary mask; out[t,b,i,j,e] ----
    float* orow = out + (size_t)(t_ * 64 + b) * (M_ELEMS * 2) + e;
    #pragma unroll
    for (int k = 0; k < EPT; ++k) {
        const int m = tid + (k << 10);
        const unsigned bits = bitmap[m >> 5];
        orow[(size_t)m * 2] = ((bits >> (m & 31)) & 1u) ? 1.0f : 0.0f;
    }
}

extern "C" void kernel_launch(void* const* d_in, const int* in_sizes, int n_in,
                              void* d_out, int out_size, void* d_ws, size_t ws_size,
                              hipStream_t stream) {
    const float* scores = (const float*)d_in[0];
    const float* gumbel = (const float*)d_in[1];
    float* out = (float*)d_out;
    const int rows = in_sizes[1] / M_ELEMS;   // 256
    gumbel_topk_kernel<<<rows, BLOCK, 0, stream>>>(scores, gumbel, out);
}

// Round 6
// 110.141 us; speedup vs baseline: 5.0895x; 1.2268x over previous
//
#include <hip/hip_runtime.h>
#include <math.h>

// GumbelSampler: iterative gumbel-softmax k-hot (k=64) over 256 rows of 16384,
// then straight-through hard top-64. One block per row (grid 256 = 1 block/CU).
//
// Round-6: round-5's candidate-compaction structure (top-1024 by initial value
// via radix histogram; full 64-iter dynamics + top-64 on ONE wave in registers)
// with the serial-phase cross-lane ops converted from ds_bpermute (__shfl,
// ~120cyc LDS latency each, unhidden with one wave) to DPP row_shr/row_bcast
// (VALU, ~8cyc) + readlane broadcast. Histogram same-address atomics on the
// flushed-to-zero tail are wave-aggregated (SQ_LDS_BANK_CONFLICT was 870k).
// Block pairs sharing output cachelines (e=0/1 of same (t,b)) are swizzled
// 128 apart -> same XCD L2 -> merged partial-line writes.
//
// Correctness envelope (validated rounds 1-5, absmax 0.0): output is exactly
// binary; only the top-64 SELECTION must match. Excluded tail (rank >1024,
// oh <= e^-27) perturbs kh by <=1e-6 vs margins O(0.01+).

#define BLOCK   1024
#define NWAVES  16
#define M_ELEMS 16384
#define EPT     16                  // elements per thread in block phases
#define KSEL    64
#define NCAND   1024                // candidate capacity
#define CPL     16                  // candidates per lane in wave0
#define NBINS   4096                // radix bins: f32 bits >> 19 (sign always 0)
#define C10     14.42695019f        // log2(e)/tau

// ---- DPP wave64 reduction helpers (CDNA keeps row_bcast15/31) ----
template <int CTRL>
__device__ __forceinline__ float dpp_f(float x, float identity) {
    return __int_as_float(__builtin_amdgcn_update_dpp(
        __float_as_int(identity), __float_as_int(x), CTRL, 0xF, 0xF, false));
}
template <int CTRL>
__device__ __forceinline__ int dpp_i(int x, int identity) {
    return __builtin_amdgcn_update_dpp(identity, x, CTRL, 0xF, 0xF, false);
}

// sum of x over 64 lanes, broadcast via readlane(63) -> uniform
__device__ __forceinline__ float wave_sum_bcast(float x) {
    x += dpp_f<0x111>(x, 0.0f);   // row_shr:1
    x += dpp_f<0x112>(x, 0.0f);   // row_shr:2
    x += dpp_f<0x114>(x, 0.0f);   // row_shr:4
    x += dpp_f<0x118>(x, 0.0f);   // row_shr:8
    x += dpp_f<0x142>(x, 0.0f);   // row_bcast:15
    x += dpp_f<0x143>(x, 0.0f);   // row_bcast:31 -> lane63 = total
    return __int_as_float(__builtin_amdgcn_readlane(__float_as_int(x), 63));
}
__device__ __forceinline__ int wave_isum_lane63(int x) {
    x += dpp_i<0x111>(x, 0);
    x += dpp_i<0x112>(x, 0);
    x += dpp_i<0x114>(x, 0);
    x += dpp_i<0x118>(x, 0);
    x += dpp_i<0x142>(x, 0);
    x += dpp_i<0x143>(x, 0);
    return x;                      // valid in lane 63
}
// (max value, min index on ties) pair-combine step
template <int CTRL>
__device__ __forceinline__ void dpp_amax(float& v, unsigned& i) {
    const float    ov = dpp_f<CTRL>(v, -INFINITY);
    const unsigned oi = (unsigned)dpp_i<CTRL>((int)i, 0x7fffffff);
    if (ov > v || (ov == v && oi < i)) { v = ov; i = oi; }
}
__device__ __forceinline__ unsigned wave_amax_idx(float v, unsigned i) {
    dpp_amax<0x111>(v, i);
    dpp_amax<0x112>(v, i);
    dpp_amax<0x114>(v, i);
    dpp_amax<0x118>(v, i);
    dpp_amax<0x142>(v, i);
    dpp_amax<0x143>(v, i);
    return (unsigned)__builtin_amdgcn_readlane((int)i, 63);
}

__global__ __launch_bounds__(BLOCK, 4) void gumbel_topk_kernel(
    const float* __restrict__ scores,
    const float* __restrict__ gumbel,
    float* __restrict__ out)
{
    const int tid  = threadIdx.x;
    const int lane = tid & 63;
    const int wid  = tid >> 6;
    // e=0/1 blocks of the same (t,b) write interleaved halves of the same
    // cachelines; put them 128 apart in blockIdx -> same XCD (round-robin %8).
    const int bid = blockIdx.x;
    const int r   = (gridDim.x == 256) ? (((bid & 127) << 1) | (bid >> 7)) : bid;
    const int t_ = r >> 7;
    const int be = r & 127;
    const int b  = be >> 1;
    const int e  = be & 1;

    __shared__ unsigned int hist[NBINS];        // 16 KB
    __shared__ float        exbuf[NCAND];       // 4 KB
    __shared__ unsigned int idxbuf[NCAND];      // 4 KB
    __shared__ unsigned int bitmap[M_ELEMS/32]; // 2 KB
    __shared__ float        redF[NWAVES];
    __shared__ unsigned int wofs[NWAVES];
    __shared__ unsigned int cutbin;
    __shared__ unsigned int candcnt;

    // ---- P0: load f0, zero hist+bitmap, row max ----
    float ex[EPT];
    {
        const float* gum = gumbel + (size_t)r * M_ELEMS;
        const float* sc  = scores + (size_t)b * (M_ELEMS * 2) + e;
        #pragma unroll
        for (int k = 0; k < EPT; ++k) {
            const int m = tid + (k << 10);
            ex[k] = sc[(size_t)m * 2] + gum[m];     // f0 for now
        }
    }
    #pragma unroll
    for (int k = 0; k < NBINS / BLOCK; ++k) hist[tid + k * BLOCK] = 0u;
    if (tid < M_ELEMS / 32) bitmap[tid] = 0u;

    float lmax = -INFINITY;
    #pragma unroll
    for (int k = 0; k < EPT; ++k) lmax = fmaxf(lmax, ex[k]);
    #pragma unroll
    for (int off = 32; off; off >>= 1) lmax = fmaxf(lmax, __shfl_xor(lmax, off));
    if (lane == 0) redF[wid] = lmax;
    __syncthreads();
    float m0 = redF[lane & (NWAVES - 1)];
    #pragma unroll
    for (int off = 1; off < NWAVES; off <<= 1)
        m0 = fmaxf(m0, __shfl_xor(m0, off));

    // ex = exp2((f0 - m0)*C10 + 60): positive, monotone in f0
    const float nb = fmaf(-m0, C10, 60.0f);
    #pragma unroll
    for (int k = 0; k < EPT; ++k)
        ex[k] = __builtin_amdgcn_exp2f(fmaf(ex[k], C10, nb));

    // ---- P1a: histogram (monotone bit-buckets); aggregate the zero pile ----
    {
        unsigned nz = 0;
        #pragma unroll
        for (int k = 0; k < EPT; ++k) {
            const unsigned key = __float_as_uint(ex[k]) >> 19;
            if (key) atomicAdd(&hist[key], 1u);
            else     ++nz;
        }
        const int zt = wave_isum_lane63((int)nz);
        if (lane == 63 && zt) atomicAdd(&hist[0], (unsigned)zt);
    }
    __syncthreads();

    // ---- P1b: wave0 finds cutoff = min bin with CntGE(bin) <= NCAND ----
    if (wid == 0) {
        unsigned part = 0;
        #pragma unroll 8
        for (int j = 0; j < NBINS / 64; ++j) part += hist[lane * (NBINS / 64) + j];
        unsigned suf = part;                       // inclusive suffix sum over lanes
        #pragma unroll
        for (int off = 1; off < 64; off <<= 1) {
            const unsigned y = __shfl_down(suf, off);
            if (lane + off < 64) suf += y;
        }
        const unsigned long long mk = __ballot(suf > NCAND);  // suf_0=16384>NCAND
        const int L = 63 - __builtin_clzll(mk);    // highest lane with suf > NCAND
        const unsigned sufNext = __shfl_down(suf, 1);
        if (lane == L) {
            unsigned running = (L == 63) ? 0u : sufNext;   // CntGE(chunk top+1)
            const int base = L * (NBINS / 64);
            for (int bb = base + (NBINS / 64) - 1; bb >= base; --bb) {
                const unsigned h = hist[bb];
                running += h;
                if (running > NCAND) {             // crossing found
                    cutbin  = (unsigned)(bb + 1);
                    candcnt = running - h;         // CntGE(bb+1) <= NCAND
                    break;
                }
            }
        }
    }
    __syncthreads();
    const unsigned cutKey = cutbin << 19;
    const unsigned nc     = candcnt;

    // ---- P1c: deterministic prefix-ordered compaction into LDS ----
    unsigned mycnt = 0, hitm = 0;
    #pragma unroll
    for (int k = 0; k < EPT; ++k) {
        const bool c = __float_as_uint(ex[k]) >= cutKey;
        hitm |= (c ? 1u : 0u) << k;
        mycnt += c ? 1u : 0u;
    }
    unsigned inc = mycnt;                          // wave inclusive prefix
    #pragma unroll
    for (int off = 1; off < 64; off <<= 1) {
        const unsigned y = __shfl_up(inc, off);
        if (lane >= off) inc += y;
    }
    if (lane == 63) wofs[wid] = inc;
    __syncthreads();
    unsigned wbase = 0;
    #pragma unroll
    for (int i = 0; i < NWAVES; ++i) wbase += (i < wid) ? wofs[i] : 0u;
    unsigned slot = wbase + inc - mycnt;
    #pragma unroll
    for (int k = 0; k < EPT; ++k) {
        if ((hitm >> k) & 1u) {
            exbuf[slot]  = ex[k];
            idxbuf[slot] = (unsigned)(tid + (k << 10));
            ++slot;
        }
    }
    if ((unsigned)tid >= nc) {                     // pad slots [nc, 1024)
        exbuf[tid]  = 0.0f;
        idxbuf[tid] = 0x7fffffffu;
    }
    __syncthreads();

    // ---- P2+P3: single-wave dynamics + top-64 (DPP only, no barriers) ----
    if (wid == 0) {
        float    cex[CPL], ckh[CPL];
        unsigned cidx[CPL];
        #pragma unroll
        for (int k = 0; k < CPL; ++k) {
            cex[k]  = exbuf[lane + (k << 6)];
            cidx[k] = idxbuf[lane + (k << 6)];
            ckh[k]  = 0.0f;
        }

        for (int it = 0; it < KSEL; ++it) {
            // local pairwise tree (regs), then 6-step DPP + readlane bcast
            float s0 = ((cex[0]+cex[1])+(cex[2]+cex[3]))
                     + ((cex[4]+cex[5])+(cex[6]+cex[7]));
            float s1 = ((cex[8]+cex[9])+(cex[10]+cex[11]))
                     + ((cex[12]+cex[13])+(cex[14]+cex[15]));
            float gsum = wave_sum_bcast(s0 + s1);

            // exponent-range rebase (wave-uniform, rare)
            const int eb = (int)((__float_as_uint(gsum) >> 23) & 0xFF);
            if (eb < 127 + 50) {
                int sh = 314 - eb;
                if (sh > 254) sh = 254;
                const float s = __uint_as_float((unsigned)sh << 23);
                #pragma unroll
                for (int k = 0; k < CPL; ++k) cex[k] *= s;
                float r0 = ((cex[0]+cex[1])+(cex[2]+cex[3]))
                         + ((cex[4]+cex[5])+(cex[6]+cex[7]));
                float r1 = ((cex[8]+cex[9])+(cex[10]+cex[11]))
                         + ((cex[12]+cex[13])+(cex[14]+cex[15]));
                gsum = wave_sum_bcast(r0 + r1);
                if (!(gsum > 0.0f)) gsum = INFINITY;
            }

            const float rsum = __builtin_amdgcn_rcpf(gsum);
            #pragma unroll
            for (int k = 0; k < CPL; ++k) {
                ckh[k] = fmaf(cex[k], rsum, ckh[k]);          // kh += oh
                const float t  = fmaf(-cex[k], rsum, 1.0f);   // 1 - oh
                const float t2 = t * t;
                const float t4 = t2 * t2;
                const float t8 = t4 * t4;
                cex[k] = cex[k] * t8 * t2;                    // ex *= t^10
            }
        }

        // top-64 straight on ckh (not needed afterwards); cached local argmax
        float    bv   = ckh[0];
        unsigned bidx = cidx[0];
        int      bk   = 0;
        #pragma unroll
        for (int k = 1; k < CPL; ++k)
            if (ckh[k] > bv || (ckh[k] == bv && cidx[k] < bidx)) {
                bv = ckh[k]; bidx = cidx[k]; bk = k;
            }

        unsigned selwin = 0xffffffffu;   // lane s holds round-s winner
        for (int s = 0; s < KSEL; ++s) {
            const unsigned gi = wave_amax_idx(bv, bidx);  // uniform winner idx
            if (lane == s) selwin = gi;
            if (gi == bidx) {            // unique global idx -> I own winner
                #pragma unroll
                for (int kk = 0; kk < CPL; ++kk)
                    if (kk == bk) ckh[kk] = -INFINITY;
                bv = ckh[0]; bidx = cidx[0]; bk = 0;
                #pragma unroll
                for (int k = 1; k < CPL; ++k)
                    if (ckh[k] > bv || (ckh[k] == bv && cidx[k] < bidx)) {
                        bv = ckh[k]; bidx = cidx[k]; bk = k;
                    }
            }
        }
        if (selwin < M_ELEMS)
            atomicOr(&bitmap[selwin >> 5], 1u << (selwin & 31));
    }
    __syncthreads();

    // ---- P4: write binary mask; out[t,b,i,j,e] ----
    float* orow = out + (size_t)(t_ * 64 + b) * (M_ELEMS * 2) + e;
    #pragma unroll
    for (int k = 0; k < EPT; ++k) {
        const int m = tid + (k << 10);
        const unsigned bits = bitmap[m >> 5];
        orow[(size_t)m * 2] = ((bits >> (m & 31)) & 1u) ? 1.0f : 0.0f;
    }
}

extern "C" void kernel_launch(void* const* d_in, const int* in_sizes, int n_in,
                              void* d_out, int out_size, void* d_ws, size_t ws_size,
                              hipStream_t stream) {
    const float* scores = (const float*)d_in[0];
    const float* gumbel = (const float*)d_in[1];
    float* out = (float*)d_out;
    const int rows = in_sizes[1] / M_ELEMS;   // 256
    gumbel_topk_kernel<<<rows, BLOCK, 0, stream>>>(scores, gumbel, out);
}

// Round 7
// 36.744 us; speedup vs baseline: 15.2557x; 2.9975x over previous
//
#include <hip/hip_runtime.h>
#include <math.h>

// GumbelSampler: iterative gumbel-softmax k-hot (k=64) over 256 rows of 16384,
// then straight-through hard top-64. One block per row (grid 256 = 1 block/CU).
//
// Round-7: candidate capacity 1024->256 (CPL=4; order-stats: rank-256 is
// ~1.4 nats below rank-64 => weight e^-14, ever-warm set is ~top-100).
// The 64-round serial argmax selection is REPLACED by an exact parallel
// rank computation: i in top-64 iff |{j: kh_j>kh_i or (kh_j==kh_i and
// idx_j<idx_i)}| < 64 -- strict total order, identical tie semantics to
// lax.top_k, 256 threads x 256 comparisons via broadcast float4 LDS reads.
// Cutoff search's serial 64-bin scan is replaced by a second wave suffix-sum.
// P0 loads vectorized (float4 gumbel, 2x float4 stride-2 scores).
//
// Correctness envelope (validated rounds 1-6, absmax 0.0): output is exactly
// binary; only the top-64 SELECTION must match.

#define BLOCK   1024
#define NWAVES  16
#define M_ELEMS 16384
#define EPT     16                  // elements per thread in block phases
#define KSEL    64
#define NCAND   256                 // candidate capacity
#define CPL     4                   // candidates per lane in wave0
#define NBINS   4096                // radix bins: f32 bits >> 19 (sign always 0)
#define C10     14.42695019f        // log2(e)/tau

// ---- DPP wave64 reduction helpers ----
template <int CTRL>
__device__ __forceinline__ float dpp_f(float x, float identity) {
    return __int_as_float(__builtin_amdgcn_update_dpp(
        __float_as_int(identity), __float_as_int(x), CTRL, 0xF, 0xF, false));
}
template <int CTRL>
__device__ __forceinline__ int dpp_i(int x, int identity) {
    return __builtin_amdgcn_update_dpp(identity, x, CTRL, 0xF, 0xF, false);
}
__device__ __forceinline__ float wave_sum_bcast(float x) {
    x += dpp_f<0x111>(x, 0.0f);   // row_shr:1
    x += dpp_f<0x112>(x, 0.0f);   // row_shr:2
    x += dpp_f<0x114>(x, 0.0f);   // row_shr:4
    x += dpp_f<0x118>(x, 0.0f);   // row_shr:8
    x += dpp_f<0x142>(x, 0.0f);   // row_bcast:15
    x += dpp_f<0x143>(x, 0.0f);   // row_bcast:31 -> lane63 = total
    return __int_as_float(__builtin_amdgcn_readlane(__float_as_int(x), 63));
}
__device__ __forceinline__ int wave_isum_lane63(int x) {
    x += dpp_i<0x111>(x, 0);
    x += dpp_i<0x112>(x, 0);
    x += dpp_i<0x114>(x, 0);
    x += dpp_i<0x118>(x, 0);
    x += dpp_i<0x142>(x, 0);
    x += dpp_i<0x143>(x, 0);
    return x;                      // valid in lane 63
}

__global__ __launch_bounds__(BLOCK, 4) void gumbel_topk_kernel(
    const float* __restrict__ scores,
    const float* __restrict__ gumbel,
    float* __restrict__ out)
{
    const int tid  = threadIdx.x;
    const int lane = tid & 63;
    const int wid  = tid >> 6;
    // e=0/1 blocks of the same (t,b) write interleaved halves of the same
    // cachelines; put them 128 apart in blockIdx -> same XCD (round-robin %8).
    const int bid = blockIdx.x;
    const int r   = (gridDim.x == 256) ? (((bid & 127) << 1) | (bid >> 7)) : bid;
    const int t_ = r >> 7;
    const int be = r & 127;
    const int b  = be >> 1;
    const int e  = be & 1;

    __shared__ unsigned int          hist[NBINS];        // 16 KB
    __shared__ __align__(16) float    exbuf[NCAND];      // 1 KB (kh after dyn)
    __shared__ __align__(16) unsigned idxbuf[NCAND];     // 1 KB
    __shared__ unsigned int          bitmap[M_ELEMS/32]; // 2 KB
    __shared__ float                 redF[NWAVES];
    __shared__ unsigned int          wofs[NWAVES];
    __shared__ unsigned int          cutbin;
    __shared__ unsigned int          candcnt;

    // ---- P0: vectorized load; element k=g*4+j -> m = tid*4 + j + g*4096 ----
    float ex[EPT];
    {
        const float* gum = gumbel + (size_t)r * M_ELEMS;
        const float* scb = scores + (size_t)b * (M_ELEMS * 2);   // aligned base
        #pragma unroll
        for (int g = 0; g < 4; ++g) {
            const int mb = (tid << 2) + (g << 12);
            const float4 gv = *reinterpret_cast<const float4*>(&gum[mb]);
            const float4 sa = *reinterpret_cast<const float4*>(&scb[(size_t)mb * 2]);
            const float4 sb = *reinterpret_cast<const float4*>(&scb[(size_t)mb * 2 + 4]);
            float s0, s1, s2, s3;
            if (e == 0) { s0 = sa.x; s1 = sa.z; s2 = sb.x; s3 = sb.z; }
            else        { s0 = sa.y; s1 = sa.w; s2 = sb.y; s3 = sb.w; }
            ex[g * 4 + 0] = s0 + gv.x;
            ex[g * 4 + 1] = s1 + gv.y;
            ex[g * 4 + 2] = s2 + gv.z;
            ex[g * 4 + 3] = s3 + gv.w;
        }
    }
    #pragma unroll
    for (int k = 0; k < NBINS / BLOCK; ++k) hist[tid + k * BLOCK] = 0u;
    if (tid < M_ELEMS / 32) bitmap[tid] = 0u;

    float lmax = -INFINITY;
    #pragma unroll
    for (int k = 0; k < EPT; ++k) lmax = fmaxf(lmax, ex[k]);
    #pragma unroll
    for (int off = 32; off; off >>= 1) lmax = fmaxf(lmax, __shfl_xor(lmax, off));
    if (lane == 0) redF[wid] = lmax;
    __syncthreads();
    float m0 = redF[lane & (NWAVES - 1)];
    #pragma unroll
    for (int off = 1; off < NWAVES; off <<= 1)
        m0 = fmaxf(m0, __shfl_xor(m0, off));

    // ex = exp2((f0 - m0)*C10 + 60): positive, monotone in f0
    const float nb = fmaf(-m0, C10, 60.0f);
    #pragma unroll
    for (int k = 0; k < EPT; ++k)
        ex[k] = __builtin_amdgcn_exp2f(fmaf(ex[k], C10, nb));

    // ---- P1a: histogram (monotone bit-buckets); aggregate the zero pile ----
    {
        unsigned nz = 0;
        #pragma unroll
        for (int k = 0; k < EPT; ++k) {
            const unsigned key = __float_as_uint(ex[k]) >> 19;
            if (key) atomicAdd(&hist[key], 1u);
            else     ++nz;
        }
        const int zt = wave_isum_lane63((int)nz);
        if (lane == 63 && zt) atomicAdd(&hist[0], (unsigned)zt);
    }
    __syncthreads();

    // ---- P1b: wave0 finds cutoff = min bin with CntGE(bin) <= NCAND ----
    // Two wave-wide suffix-sums + ballots; no serial bin scan.
    if (wid == 0) {
        unsigned part = 0;
        #pragma unroll 8
        for (int j = 0; j < NBINS / 64; ++j) part += hist[lane * (NBINS / 64) + j];
        unsigned suf = part;                       // inclusive suffix over lanes
        #pragma unroll
        for (int off = 1; off < 64; off <<= 1) {
            const unsigned y = __shfl_down(suf, off);
            if (lane + off < 64) suf += y;
        }
        const unsigned long long mk = __ballot(suf > NCAND);  // lane0 total>NCAND
        const int L = 63 - __builtin_clzll(mk);    // highest lane with suf > NCAND
        const unsigned sufNext = (L < 63) ? (unsigned)__shfl(suf, L + 1) : 0u;
        // per-bin suffix within chunk L
        unsigned sufB = hist[L * (NBINS / 64) + lane];
        #pragma unroll
        for (int off = 1; off < 64; off <<= 1) {
            const unsigned y = __shfl_down(sufB, off);
            if (lane + off < 64) sufB += y;
        }
        sufB += sufNext;                           // = CntGE(L*64 + lane)
        const unsigned long long mk2 = __ballot(sufB > NCAND);  // lane0 set
        const int Lb = 63 - __builtin_clzll(mk2);
        const unsigned cc = (Lb < 63) ? (unsigned)__shfl(sufB, Lb + 1) : sufNext;
        if (lane == 0) { cutbin = (unsigned)(L * (NBINS / 64) + Lb + 1); candcnt = cc; }
    }
    __syncthreads();
    const unsigned cutKey = cutbin << 19;
    const unsigned nc     = candcnt;

    // ---- P1c: deterministic prefix-ordered compaction into LDS ----
    unsigned mycnt = 0, hitm = 0;
    #pragma unroll
    for (int k = 0; k < EPT; ++k) {
        const bool c = __float_as_uint(ex[k]) >= cutKey;
        hitm |= (c ? 1u : 0u) << k;
        mycnt += c ? 1u : 0u;
    }
    unsigned inc = mycnt;                          // wave inclusive prefix
    #pragma unroll
    for (int off = 1; off < 64; off <<= 1) {
        const unsigned y = __shfl_up(inc, off);
        if (lane >= off) inc += y;
    }
    if (lane == 63) wofs[wid] = inc;
    __syncthreads();
    unsigned wbase = 0;
    #pragma unroll
    for (int i = 0; i < NWAVES; ++i) wbase += (i < wid) ? wofs[i] : 0u;
    unsigned slot = wbase + inc - mycnt;
    #pragma unroll
    for (int k = 0; k < EPT; ++k) {
        if ((hitm >> k) & 1u) {
            exbuf[slot]  = ex[k];
            idxbuf[slot] = (unsigned)((tid << 2) + (k & 3) + ((k >> 2) << 12));
            ++slot;
        }
    }
    if ((unsigned)tid >= nc && tid < NCAND) {      // pad slots [nc, 256)
        exbuf[tid]  = 0.0f;
        idxbuf[tid] = 0x7fffffffu;
    }
    __syncthreads();

    // ---- P2: single-wave dynamics (64 iters, DPP-only, no barriers) ----
    if (wid == 0) {
        float cex[CPL], ckh[CPL];
        #pragma unroll
        for (int k = 0; k < CPL; ++k) {
            cex[k] = exbuf[lane + (k << 6)];
            ckh[k] = 0.0f;
        }
        for (int it = 0; it < KSEL; ++it) {
            float gsum = wave_sum_bcast((cex[0] + cex[1]) + (cex[2] + cex[3]));
            // exponent-range rebase (wave-uniform, rare)
            const int eb = (int)((__float_as_uint(gsum) >> 23) & 0xFF);
            if (eb < 127 + 50) {
                int sh = 314 - eb;
                if (sh > 254) sh = 254;
                const float s = __uint_as_float((unsigned)sh << 23);
                #pragma unroll
                for (int k = 0; k < CPL; ++k) cex[k] *= s;
                gsum = wave_sum_bcast((cex[0] + cex[1]) + (cex[2] + cex[3]));
                if (!(gsum > 0.0f)) gsum = INFINITY;
            }
            const float rsum = __builtin_amdgcn_rcpf(gsum);
            #pragma unroll
            for (int k = 0; k < CPL; ++k) {
                ckh[k] = fmaf(cex[k], rsum, ckh[k]);          // kh += oh
                const float t  = fmaf(-cex[k], rsum, 1.0f);   // 1 - oh
                const float t2 = t * t;
                const float t4 = t2 * t2;
                const float t8 = t4 * t4;
                cex[k] = cex[k] * t8 * t2;                    // ex *= t^10
            }
        }
        #pragma unroll
        for (int k = 0; k < CPL; ++k) exbuf[lane + (k << 6)] = ckh[k]; // kh -> LDS
    }
    __syncthreads();

    // ---- P3: parallel exact top-64 by rank (matches lax.top_k ties) ----
    // rank_i = |{j: kh_j > kh_i or (kh_j == kh_i and idx_j < idx_i)}|
    if (tid < NCAND) {
        const float    myv = exbuf[tid];
        const unsigned myi = idxbuf[tid];
        unsigned rank = 0;
        #pragma unroll 8
        for (int j = 0; j < NCAND; j += 4) {
            const float4 v  = *reinterpret_cast<const float4*>(&exbuf[j]);
            const uint4  ii = *reinterpret_cast<const uint4*>(&idxbuf[j]);
            rank += (v.x > myv || (v.x == myv && ii.x < myi)) ? 1u : 0u;
            rank += (v.y > myv || (v.y == myv && ii.y < myi)) ? 1u : 0u;
            rank += (v.z > myv || (v.z == myv && ii.z < myi)) ? 1u : 0u;
            rank += (v.w > myv || (v.w == myv && ii.w < myi)) ? 1u : 0u;
        }
        if (rank < KSEL && myi < M_ELEMS)
            atomicOr(&bitmap[myi >> 5], 1u << (myi & 31));
    }
    __syncthreads();

    // ---- P4: write binary mask; out[t,b,i,j,e] ----
    float* orow = out + (size_t)(t_ * 64 + b) * (M_ELEMS * 2) + e;
    #pragma unroll
    for (int k = 0; k < EPT; ++k) {
        const int m = tid + (k << 10);
        const unsigned bits = bitmap[m >> 5];
        orow[(size_t)m * 2] = ((bits >> (m & 31)) & 1u) ? 1.0f : 0.0f;
    }
}

extern "C" void kernel_launch(void* const* d_in, const int* in_sizes, int n_in,
                              void* d_out, int out_size, void* d_ws, size_t ws_size,
                              hipStream_t stream) {
    const float* scores = (const float*)d_in[0];
    const float* gumbel = (const float*)d_in[1];
    float* out = (float*)d_out;
    const int rows = in_sizes[1] / M_ELEMS;   // 256
    gumbel_topk_kernel<<<rows, BLOCK, 0, stream>>>(scores, gumbel, out);
}

// Round 8
// 34.187 us; speedup vs baseline: 16.3968x; 1.0748x over previous
//
#include <hip/hip_runtime.h>
#include <math.h>

// GumbelSampler: iterative gumbel-softmax k-hot (k=64) over 256 rows of 16384,
// then straight-through hard top-64. One block per row (grid 256 = 1 block/CU).
//
// Round-8: overlap + tail elimination on round-7's validated structure.
//  - Output zero-fill issues from waves 1-15 WHILE wave0 runs the 64-iter
//    dynamics (stores drain at each wave's own pre-barrier vmcnt(0), so the
//    later 1.0f stores are ordered after the zeros).
//  - Rank winners write 1.0f DIRECTLY to their output slot: bitmap array,
//    its zero-init, atomicOr, and the final read-back pass are deleted.
//  - One fewer barrier (6 total).
// Selection math (ex-space histogram -> top-256 compaction -> single-wave
// dynamics -> exact parallel rank, lax.top_k tie semantics) is bit-identical
// to round 7 (absmax 0.0).

#define BLOCK   1024
#define NWAVES  16
#define M_ELEMS 16384
#define EPT     16                  // elements per thread in block phases
#define KSEL    64
#define NCAND   256                 // candidate capacity
#define CPL     4                   // candidates per lane in wave0
#define NBINS   4096                // radix bins: f32 bits >> 19 (sign always 0)
#define C10     14.42695019f        // log2(e)/tau

// ---- DPP wave64 reduction helpers ----
template <int CTRL>
__device__ __forceinline__ float dpp_f(float x, float identity) {
    return __int_as_float(__builtin_amdgcn_update_dpp(
        __float_as_int(identity), __float_as_int(x), CTRL, 0xF, 0xF, false));
}
template <int CTRL>
__device__ __forceinline__ int dpp_i(int x, int identity) {
    return __builtin_amdgcn_update_dpp(identity, x, CTRL, 0xF, 0xF, false);
}
__device__ __forceinline__ float wave_sum_bcast(float x) {
    x += dpp_f<0x111>(x, 0.0f);   // row_shr:1
    x += dpp_f<0x112>(x, 0.0f);   // row_shr:2
    x += dpp_f<0x114>(x, 0.0f);   // row_shr:4
    x += dpp_f<0x118>(x, 0.0f);   // row_shr:8
    x += dpp_f<0x142>(x, 0.0f);   // row_bcast:15
    x += dpp_f<0x143>(x, 0.0f);   // row_bcast:31 -> lane63 = total
    return __int_as_float(__builtin_amdgcn_readlane(__float_as_int(x), 63));
}
__device__ __forceinline__ int wave_isum_lane63(int x) {
    x += dpp_i<0x111>(x, 0);
    x += dpp_i<0x112>(x, 0);
    x += dpp_i<0x114>(x, 0);
    x += dpp_i<0x118>(x, 0);
    x += dpp_i<0x142>(x, 0);
    x += dpp_i<0x143>(x, 0);
    return x;                      // valid in lane 63
}

__global__ __launch_bounds__(BLOCK, 4) void gumbel_topk_kernel(
    const float* __restrict__ scores,
    const float* __restrict__ gumbel,
    float* __restrict__ out)
{
    const int tid  = threadIdx.x;
    const int lane = tid & 63;
    const int wid  = tid >> 6;
    // e=0/1 blocks of the same (t,b) write interleaved halves of the same
    // cachelines; put them 128 apart in blockIdx -> same XCD (round-robin %8).
    const int bid = blockIdx.x;
    const int r   = (gridDim.x == 256) ? (((bid & 127) << 1) | (bid >> 7)) : bid;
    const int t_ = r >> 7;
    const int be = r & 127;
    const int b  = be >> 1;
    const int e  = be & 1;

    __shared__ unsigned int          hist[NBINS];        // 16 KB
    __shared__ __align__(16) float    exbuf[NCAND];      // 1 KB (kh after dyn)
    __shared__ __align__(16) unsigned idxbuf[NCAND];     // 1 KB
    __shared__ float                 redF[NWAVES];
    __shared__ unsigned int          wofs[NWAVES];
    __shared__ unsigned int          cutbin;
    __shared__ unsigned int          candcnt;

    float* orow = out + (size_t)(t_ * 64 + b) * (M_ELEMS * 2) + e;

    // ---- P0: vectorized load; element k=g*4+j -> m = tid*4 + j + g*4096 ----
    float ex[EPT];
    {
        const float* gum = gumbel + (size_t)r * M_ELEMS;
        const float* scb = scores + (size_t)b * (M_ELEMS * 2);   // aligned base
        #pragma unroll
        for (int g = 0; g < 4; ++g) {
            const int mb = (tid << 2) + (g << 12);
            const float4 gv = *reinterpret_cast<const float4*>(&gum[mb]);
            const float4 sa = *reinterpret_cast<const float4*>(&scb[(size_t)mb * 2]);
            const float4 sb = *reinterpret_cast<const float4*>(&scb[(size_t)mb * 2 + 4]);
            float s0, s1, s2, s3;
            if (e == 0) { s0 = sa.x; s1 = sa.z; s2 = sb.x; s3 = sb.z; }
            else        { s0 = sa.y; s1 = sa.w; s2 = sb.y; s3 = sb.w; }
            ex[g * 4 + 0] = s0 + gv.x;
            ex[g * 4 + 1] = s1 + gv.y;
            ex[g * 4 + 2] = s2 + gv.z;
            ex[g * 4 + 3] = s3 + gv.w;
        }
    }
    #pragma unroll
    for (int k = 0; k < NBINS / BLOCK; ++k) hist[tid + k * BLOCK] = 0u;

    float lmax = -INFINITY;
    #pragma unroll
    for (int k = 0; k < EPT; ++k) lmax = fmaxf(lmax, ex[k]);
    #pragma unroll
    for (int off = 32; off; off >>= 1) lmax = fmaxf(lmax, __shfl_xor(lmax, off));
    if (lane == 0) redF[wid] = lmax;
    __syncthreads();                                   // B1: hist zeroed, redF
    float m0 = redF[lane & (NWAVES - 1)];
    #pragma unroll
    for (int off = 1; off < NWAVES; off <<= 1)
        m0 = fmaxf(m0, __shfl_xor(m0, off));

    // ex = exp2((f0 - m0)*C10 + 60): positive, monotone in f0
    const float nb = fmaf(-m0, C10, 60.0f);
    #pragma unroll
    for (int k = 0; k < EPT; ++k)
        ex[k] = __builtin_amdgcn_exp2f(fmaf(ex[k], C10, nb));

    // ---- P1a: histogram (monotone bit-buckets); aggregate the zero pile ----
    {
        unsigned nz = 0;
        #pragma unroll
        for (int k = 0; k < EPT; ++k) {
            const unsigned key = __float_as_uint(ex[k]) >> 19;
            if (key) atomicAdd(&hist[key], 1u);
            else     ++nz;
        }
        const int zt = wave_isum_lane63((int)nz);
        if (lane == 63 && zt) atomicAdd(&hist[0], (unsigned)zt);
    }
    __syncthreads();                                   // B2: hist complete

    // ---- P1b: wave0 finds cutoff = min bin with CntGE(bin) <= NCAND ----
    if (wid == 0) {
        unsigned part = 0;
        #pragma unroll 8
        for (int j = 0; j < NBINS / 64; ++j) part += hist[lane * (NBINS / 64) + j];
        unsigned suf = part;                       // inclusive suffix over lanes
        #pragma unroll
        for (int off = 1; off < 64; off <<= 1) {
            const unsigned y = __shfl_down(suf, off);
            if (lane + off < 64) suf += y;
        }
        const unsigned long long mk = __ballot(suf > NCAND);  // lane0 total>NCAND
        const int L = 63 - __builtin_clzll(mk);    // highest lane with suf > NCAND
        const unsigned sufNext = (L < 63) ? (unsigned)__shfl(suf, L + 1) : 0u;
        // per-bin suffix within chunk L
        unsigned sufB = hist[L * (NBINS / 64) + lane];
        #pragma unroll
        for (int off = 1; off < 64; off <<= 1) {
            const unsigned y = __shfl_down(sufB, off);
            if (lane + off < 64) sufB += y;
        }
        sufB += sufNext;                           // = CntGE(L*64 + lane)
        const unsigned long long mk2 = __ballot(sufB > NCAND);
        const int Lb = 63 - __builtin_clzll(mk2);
        const unsigned cc = (Lb < 63) ? (unsigned)__shfl(sufB, Lb + 1) : sufNext;
        if (lane == 0) { cutbin = (unsigned)(L * (NBINS / 64) + Lb + 1); candcnt = cc; }
    }
    __syncthreads();                                   // B3: cutbin ready
    const unsigned cutKey = cutbin << 19;
    const unsigned nc     = candcnt;

    // ---- P1c: deterministic prefix-ordered compaction into LDS ----
    unsigned mycnt = 0, hitm = 0;
    #pragma unroll
    for (int k = 0; k < EPT; ++k) {
        const bool c = __float_as_uint(ex[k]) >= cutKey;
        hitm |= (c ? 1u : 0u) << k;
        mycnt += c ? 1u : 0u;
    }
    unsigned inc = mycnt;                          // wave inclusive prefix
    #pragma unroll
    for (int off = 1; off < 64; off <<= 1) {
        const unsigned y = __shfl_up(inc, off);
        if (lane >= off) inc += y;
    }
    if (lane == 63) wofs[wid] = inc;
    __syncthreads();                                   // B4: wofs ready
    unsigned wbase = 0;
    #pragma unroll
    for (int i = 0; i < NWAVES; ++i) wbase += (i < wid) ? wofs[i] : 0u;
    unsigned slot = wbase + inc - mycnt;
    #pragma unroll
    for (int k = 0; k < EPT; ++k) {
        if ((hitm >> k) & 1u) {
            exbuf[slot]  = ex[k];
            idxbuf[slot] = (unsigned)((tid << 2) + (k & 3) + ((k >> 2) << 12));
            ++slot;
        }
    }
    if ((unsigned)tid >= nc && tid < NCAND) {      // pad slots [nc, 256)
        exbuf[tid]  = 0.0f;
        idxbuf[tid] = 0x7fffffffu;
    }
    __syncthreads();                                   // B5: candidates ready

    // ---- P2: wave0 dynamics (DPP-only)  ||  waves 1-15 zero the output ----
    if (wid == 0) {
        float cex[CPL], ckh[CPL];
        #pragma unroll
        for (int k = 0; k < CPL; ++k) {
            cex[k] = exbuf[lane + (k << 6)];
            ckh[k] = 0.0f;
        }
        for (int it = 0; it < KSEL; ++it) {
            float gsum = wave_sum_bcast((cex[0] + cex[1]) + (cex[2] + cex[3]));
            // exponent-range rebase (wave-uniform, rare)
            const int eb = (int)((__float_as_uint(gsum) >> 23) & 0xFF);
            if (eb < 127 + 50) {
                int sh = 314 - eb;
                if (sh > 254) sh = 254;
                const float s = __uint_as_float((unsigned)sh << 23);
                #pragma unroll
                for (int k = 0; k < CPL; ++k) cex[k] *= s;
                gsum = wave_sum_bcast((cex[0] + cex[1]) + (cex[2] + cex[3]));
                if (!(gsum > 0.0f)) gsum = INFINITY;
            }
            const float rsum = __builtin_amdgcn_rcpf(gsum);
            #pragma unroll
            for (int k = 0; k < CPL; ++k) {
                ckh[k] = fmaf(cex[k], rsum, ckh[k]);          // kh += oh
                const float t  = fmaf(-cex[k], rsum, 1.0f);   // 1 - oh
                const float t2 = t * t;
                const float t4 = t2 * t2;
                const float t8 = t4 * t4;
                cex[k] = cex[k] * t8 * t2;                    // ex *= t^10
            }
        }
        #pragma unroll
        for (int k = 0; k < CPL; ++k) exbuf[lane + (k << 6)] = ckh[k]; // kh -> LDS
    } else {
        // zero-fill this row's output (stride-960 covers all 16384 residues);
        // stores drain at this wave's own vmcnt(0) before B6, so the 1.0f
        // stores issued after B6 are ordered behind them.
        for (int m = tid - 64; m < M_ELEMS; m += BLOCK - 64)
            orow[(size_t)m * 2] = 0.0f;
    }
    __syncthreads();                                   // B6: kh + zeros done

    // ---- P3: parallel exact top-64 by rank; winners write 1.0f directly ----
    // rank_i = |{j: kh_j > kh_i or (kh_j == kh_i and idx_j < idx_i)}|
    if (tid < NCAND) {
        const float    myv = exbuf[tid];
        const unsigned myi = idxbuf[tid];
        unsigned rank = 0;
        #pragma unroll 8
        for (int j = 0; j < NCAND; j += 4) {
            const float4 v  = *reinterpret_cast<const float4*>(&exbuf[j]);
            const uint4  ii = *reinterpret_cast<const uint4*>(&idxbuf[j]);
            rank += (v.x > myv || (v.x == myv && ii.x < myi)) ? 1u : 0u;
            rank += (v.y > myv || (v.y == myv && ii.y < myi)) ? 1u : 0u;
            rank += (v.z > myv || (v.z == myv && ii.z < myi)) ? 1u : 0u;
            rank += (v.w > myv || (v.w == myv && ii.w < myi)) ? 1u : 0u;
        }
        if (rank < KSEL && myi < M_ELEMS)
            orow[(size_t)myi * 2] = 1.0f;
    }
}

extern "C" void kernel_launch(void* const* d_in, const int* in_sizes, int n_in,
                              void* d_out, int out_size, void* d_ws, size_t ws_size,
                              hipStream_t stream) {
    const float* scores = (const float*)d_in[0];
    const float* gumbel = (const float*)d_in[1];
    float* out = (float*)d_out;
    const int rows = in_sizes[1] / M_ELEMS;   // 256
    gumbel_topk_kernel<<<rows, BLOCK, 0, stream>>>(scores, gumbel, out);
}

// Round 9
// 33.255 us; speedup vs baseline: 16.8566x; 1.0280x over previous
//
#include <hip/hip_runtime.h>
#include <math.h>

// GumbelSampler: iterative gumbel-softmax k-hot (k=64) over 256 rows of 16384,
// then straight-through hard top-64. One block per row (grid 256 = 1 block/CU).
//
// Round-9 (on round-8's validated structure):
//  - Histogram bins f0 BIT-PATTERNS (monotone sign-flip transform) instead of
//    ex: the block-wide max reduction and all 16 exp2/thread are deleted; exp
//    is applied by wave0 to the 256 candidates only (bit-identical values).
//  - Cutoff scan stage-1 de-conflicted: hist[lane*64+((j+lane)&63)] rotation
//    (old pattern put all 64 lanes on one bank x 64 reads -> ~32-way conflict,
//    the bulk of the 558k SQ_LDS_BANK_CONFLICT).
//  - All shfl (ds_bpermute ~120cyc/step) scan chains replaced with DPP
//    prefix scans (row_shr 1/2/4/8 + row_bcast15 mask 0xA / bcast31 mask 0xC)
//    + ballot/ctz/readlane. Cut condition reformulated via CntLT >= 16128.
// Selection math (candidate set at the e^-27 tail aside) is value-identical
// to rounds 7/8 (absmax 0.0): exact parallel rank, lax.top_k tie semantics.

#define BLOCK   1024
#define NWAVES  16
#define M_ELEMS 16384
#define EPT     16                  // elements per thread in block phases
#define KSEL    64
#define NCAND   256                 // candidate capacity
#define CPL     4                   // candidates per lane in wave0
#define NBINS   4096                // radix bins: transformed f0 bits >> 20
#define THRESH  (M_ELEMS - NCAND)   // 16128: cut where CntLT >= THRESH
#define C10     14.42695019f        // log2(e)/tau

// ---- DPP wave64 helpers ----
template <int CTRL, int RM = 0xF>
__device__ __forceinline__ float dpp_f(float x, float identity) {
    return __int_as_float(__builtin_amdgcn_update_dpp(
        __float_as_int(identity), __float_as_int(x), CTRL, RM, 0xF, false));
}
template <int CTRL, int RM = 0xF>
__device__ __forceinline__ unsigned dpp_u(unsigned x, unsigned identity) {
    return (unsigned)__builtin_amdgcn_update_dpp(
        (int)identity, (int)x, CTRL, RM, 0xF, false);
}
// sum over 64 lanes -> uniform (reduce-to-lane63 + readlane)
__device__ __forceinline__ float wave_sum_bcast(float x) {
    x += dpp_f<0x111>(x, 0.0f);   // row_shr:1
    x += dpp_f<0x112>(x, 0.0f);   // row_shr:2
    x += dpp_f<0x114>(x, 0.0f);   // row_shr:4
    x += dpp_f<0x118>(x, 0.0f);   // row_shr:8
    x += dpp_f<0x142>(x, 0.0f);   // row_bcast:15
    x += dpp_f<0x143>(x, 0.0f);   // row_bcast:31 -> lane63 = total
    return __int_as_float(__builtin_amdgcn_readlane(__float_as_int(x), 63));
}
__device__ __forceinline__ float wave_fmax_bcast(float x) {
    x = fmaxf(x, dpp_f<0x111>(x, -INFINITY));
    x = fmaxf(x, dpp_f<0x112>(x, -INFINITY));
    x = fmaxf(x, dpp_f<0x114>(x, -INFINITY));
    x = fmaxf(x, dpp_f<0x118>(x, -INFINITY));
    x = fmaxf(x, dpp_f<0x142>(x, -INFINITY));
    x = fmaxf(x, dpp_f<0x143>(x, -INFINITY));
    return __int_as_float(__builtin_amdgcn_readlane(__float_as_int(x), 63));
}
// inclusive prefix sum over 64 lanes (LLVM atomic-optimizer sequence)
__device__ __forceinline__ unsigned wave_prefix_incl(unsigned x) {
    x += dpp_u<0x111>(x, 0u);          // row_shr:1
    x += dpp_u<0x112>(x, 0u);          // row_shr:2
    x += dpp_u<0x114>(x, 0u);          // row_shr:4
    x += dpp_u<0x118>(x, 0u);          // row_shr:8
    x += dpp_u<0x142, 0xA>(x, 0u);     // row_bcast:15 -> rows 1,3
    x += dpp_u<0x143, 0xC>(x, 0u);     // row_bcast:31 -> rows 2,3
    return x;
}

__global__ __launch_bounds__(BLOCK, 4) void gumbel_topk_kernel(
    const float* __restrict__ scores,
    const float* __restrict__ gumbel,
    float* __restrict__ out)
{
    const int tid  = threadIdx.x;
    const int lane = tid & 63;
    const int wid  = tid >> 6;
    // e=0/1 blocks of the same (t,b) write interleaved halves of the same
    // cachelines; put them 128 apart in blockIdx -> same XCD (round-robin %8).
    const int bid = blockIdx.x;
    const int r   = (gridDim.x == 256) ? (((bid & 127) << 1) | (bid >> 7)) : bid;
    const int t_ = r >> 7;
    const int be = r & 127;
    const int b  = be >> 1;
    const int e  = be & 1;

    __shared__ unsigned int          hist[NBINS];        // 16 KB
    __shared__ __align__(16) float    exbuf[NCAND];      // f0 -> kh
    __shared__ __align__(16) unsigned idxbuf[NCAND];
    __shared__ unsigned int          wofs[NWAVES];
    __shared__ unsigned int          cutbin;
    __shared__ unsigned int          candcnt;

    float* orow = out + (size_t)(t_ * 64 + b) * (M_ELEMS * 2) + e;

    // ---- P0: vectorized load; element k=g*4+j -> m = tid*4 + j + g*4096 ----
    float fv[EPT];
    {
        const float* gum = gumbel + (size_t)r * M_ELEMS;
        const float* scb = scores + (size_t)b * (M_ELEMS * 2);   // aligned base
        #pragma unroll
        for (int g = 0; g < 4; ++g) {
            const int mb = (tid << 2) + (g << 12);
            const float4 gv = *reinterpret_cast<const float4*>(&gum[mb]);
            const float4 sa = *reinterpret_cast<const float4*>(&scb[(size_t)mb * 2]);
            const float4 sb = *reinterpret_cast<const float4*>(&scb[(size_t)mb * 2 + 4]);
            float s0, s1, s2, s3;
            if (e == 0) { s0 = sa.x; s1 = sa.z; s2 = sb.x; s3 = sb.z; }
            else        { s0 = sa.y; s1 = sa.w; s2 = sb.y; s3 = sb.w; }
            fv[g * 4 + 0] = s0 + gv.x;
            fv[g * 4 + 1] = s1 + gv.y;
            fv[g * 4 + 2] = s2 + gv.z;
            fv[g * 4 + 3] = s3 + gv.w;
        }
    }
    #pragma unroll
    for (int k = 0; k < NBINS / BLOCK; ++k) hist[tid + k * BLOCK] = 0u;
    __syncthreads();                                   // B1: hist zeroed

    // ---- P1a: histogram of monotone-transformed f0 bits ----
    #pragma unroll
    for (int k = 0; k < EPT; ++k) {
        const unsigned u  = __float_as_uint(fv[k]);
        const unsigned tk = u ^ (unsigned)(((int)u >> 31) | 0x80000000);
        atomicAdd(&hist[tk >> 20], 1u);
    }
    __syncthreads();                                   // B2: hist complete

    // ---- P1b: wave0 cutoff: min bin B with CntLT(B) >= 16128 ----
    if (wid == 0) {
        unsigned part = 0;
        #pragma unroll 8
        for (int j = 0; j < 64; ++j)                   // rotated: bank-spread
            part += hist[(lane << 6) + ((j + lane) & 63)];
        const unsigned P = wave_prefix_incl(part);     // CntLT(64*(lane+1))
        const unsigned long long mk = __ballot(P >= THRESH);  // lane63 always
        const int L = __builtin_ctzll(mk);             // crossing chunk
        const unsigned base = (L > 0)
            ? (unsigned)__builtin_amdgcn_readlane((int)P, L - 1) : 0u;
        const unsigned h2 = hist[(L << 6) + lane];     // consecutive: no conflict
        const unsigned p2 = wave_prefix_incl(h2) + base; // CntLT(L*64+lane+1)
        const unsigned long long mk2 = __ballot(p2 >= THRESH);
        const int j2 = __builtin_ctzll(mk2);           // crossing bin in chunk
        if (lane == 0) {
            cutbin  = (unsigned)((L << 6) + j2 + 1);
            candcnt = M_ELEMS - (unsigned)__builtin_amdgcn_readlane((int)p2, j2);
        }
    }
    __syncthreads();                                   // B3: cut ready
    const unsigned cutKey = cutbin << 20;
    const unsigned nc     = candcnt;

    // ---- P1c: deterministic prefix-ordered compaction (stores f0) ----
    unsigned mycnt = 0, hitm = 0;
    #pragma unroll
    for (int k = 0; k < EPT; ++k) {
        const unsigned u  = __float_as_uint(fv[k]);
        const unsigned tk = u ^ (unsigned)(((int)u >> 31) | 0x80000000);
        const bool c = tk >= cutKey;
        hitm |= (c ? 1u : 0u) << k;
        mycnt += c ? 1u : 0u;
    }
    const unsigned inc = wave_prefix_incl(mycnt);      // DPP, no bpermute
    if (lane == 63) wofs[wid] = inc;
    __syncthreads();                                   // B4: wofs ready
    unsigned wbase = 0;
    #pragma unroll
    for (int i = 0; i < NWAVES; ++i) wbase += (i < wid) ? wofs[i] : 0u;
    unsigned slot = wbase + inc - mycnt;
    #pragma unroll
    for (int k = 0; k < EPT; ++k) {
        if ((hitm >> k) & 1u) {
            exbuf[slot]  = fv[k];
            idxbuf[slot] = (unsigned)((tid << 2) + (k & 3) + ((k >> 2) << 12));
            ++slot;
        }
    }
    if ((unsigned)tid >= nc && tid < NCAND) {          // pad slots [nc, 256)
        exbuf[tid]  = -INFINITY;                       // -> ex = 0 exactly
        idxbuf[tid] = 0x7fffffffu;
    }
    __syncthreads();                                   // B5: candidates ready

    // ---- P2: wave0 dynamics (DPP-only)  ||  waves 1-15 zero the output ----
    if (wid == 0) {
        float cf[CPL], cex[CPL], ckh[CPL];
        #pragma unroll
        for (int k = 0; k < CPL; ++k) cf[k] = exbuf[lane + (k << 6)];
        float cmax = fmaxf(fmaxf(cf[0], cf[1]), fmaxf(cf[2], cf[3]));
        cmax = wave_fmax_bcast(cmax);                  // == row max (always cand)
        const float nbw = fmaf(-cmax, C10, 60.0f);
        #pragma unroll
        for (int k = 0; k < CPL; ++k) {
            cex[k] = __builtin_amdgcn_exp2f(fmaf(cf[k], C10, nbw));
            ckh[k] = 0.0f;
        }
        for (int it = 0; it < KSEL; ++it) {
            float gsum = wave_sum_bcast((cex[0] + cex[1]) + (cex[2] + cex[3]));
            // exponent-range rebase (wave-uniform, rare)
            const int eb = (int)((__float_as_uint(gsum) >> 23) & 0xFF);
            if (eb < 127 + 50) {
                int sh = 314 - eb;
                if (sh > 254) sh = 254;
                const float s = __uint_as_float((unsigned)sh << 23);
                #pragma unroll
                for (int k = 0; k < CPL; ++k) cex[k] *= s;
                gsum = wave_sum_bcast((cex[0] + cex[1]) + (cex[2] + cex[3]));
                if (!(gsum > 0.0f)) gsum = INFINITY;
            }
            const float rsum = __builtin_amdgcn_rcpf(gsum);
            #pragma unroll
            for (int k = 0; k < CPL; ++k) {
                ckh[k] = fmaf(cex[k], rsum, ckh[k]);          // kh += oh
                const float t  = fmaf(-cex[k], rsum, 1.0f);   // 1 - oh
                const float t2 = t * t;
                const float t4 = t2 * t2;
                const float t8 = t4 * t4;
                cex[k] = cex[k] * t8 * t2;                    // ex *= t^10
            }
        }
        #pragma unroll
        for (int k = 0; k < CPL; ++k) exbuf[lane + (k << 6)] = ckh[k]; // kh
    } else {
        // zero-fill this row's output; stores drain at this wave's vmcnt(0)
        // before B6, ordering them behind the 1.0f stores issued after B6.
        for (int m = tid - 64; m < M_ELEMS; m += BLOCK - 64)
            orow[(size_t)m * 2] = 0.0f;
    }
    __syncthreads();                                   // B6: kh + zeros done

    // ---- P3: parallel exact top-64 by rank; winners write 1.0f directly ----
    // rank_i = |{j: kh_j > kh_i or (kh_j == kh_i and idx_j < idx_i)}|
    if (tid < NCAND) {
        const float    myv = exbuf[tid];
        const unsigned myi = idxbuf[tid];
        unsigned rank = 0;
        #pragma unroll 8
        for (int j = 0; j < NCAND; j += 4) {
            const float4 v  = *reinterpret_cast<const float4*>(&exbuf[j]);
            const uint4  ii = *reinterpret_cast<const uint4*>(&idxbuf[j]);
            rank += (v.x > myv || (v.x == myv && ii.x < myi)) ? 1u : 0u;
            rank += (v.y > myv || (v.y == myv && ii.y < myi)) ? 1u : 0u;
            rank += (v.z > myv || (v.z == myv && ii.z < myi)) ? 1u : 0u;
            rank += (v.w > myv || (v.w == myv && ii.w < myi)) ? 1u : 0u;
        }
        if (rank < KSEL && myi < M_ELEMS)
            orow[(size_t)myi * 2] = 1.0f;
    }
}

extern "C" void kernel_launch(void* const* d_in, const int* in_sizes, int n_in,
                              void* d_out, int out_size, void* d_ws, size_t ws_size,
                              hipStream_t stream) {
    const float* scores = (const float*)d_in[0];
    const float* gumbel = (const float*)d_in[1];
    float* out = (float*)d_out;
    const int rows = in_sizes[1] / M_ELEMS;   // 256
    gumbel_topk_kernel<<<rows, BLOCK, 0, stream>>>(scores, gumbel, out);
}